// Round 1
// baseline (315.298 us; speedup 1.0000x reference)
//
#include <hip/hip_runtime.h>
#include <hip/hip_bf16.h>
#include <stdint.h>

// Problem constants (B=4096, V=512, H=64)
#define BB 4096
#define VV 512
#define HH 64

typedef short bf16x8 __attribute__((ext_vector_type(8)));
typedef float floatx4 __attribute__((ext_vector_type(4)));

typedef const __attribute__((address_space(1))) void g_void;
typedef __attribute__((address_space(3))) void l_void;

__device__ __forceinline__ void gload_lds16(const void* g, void* l) {
    __builtin_amdgcn_global_load_lds((g_void*)g, (l_void*)l, 16, 0, 0);
}

__device__ __forceinline__ unsigned short f2bf_rne(float f) {
    unsigned int u = __float_as_uint(f);
    u += 0x7FFFu + ((u >> 16) & 1u);   // round-to-nearest-even
    return (unsigned short)(u >> 16);
}

// ---------------------------------------------------------------- adj output
__global__ __launch_bounds__(256) void adj_kernel(const float* __restrict__ logits,
                                                  float* __restrict__ adj_out) {
    int idx = blockIdx.x * 256 + threadIdx.x;      // 0..262143
    int v = idx >> 9;
    int u = idx & (VV - 1);
    // sigmoid(x) > 0.5  <=>  x > 0 ; zero diagonal
    adj_out[idx] = (logits[idx] > 0.0f && v != u) ? 1.0f : 0.0f;
}

// ---------------------------------------------------------------- X -> bf16
__global__ __launch_bounds__(256) void x_convert_kernel(const float* __restrict__ X,
                                                        unsigned short* __restrict__ Xbf) {
    int idx = blockIdx.x * 256 + threadIdx.x;      // x4 elements
    float4 v = ((const float4*)X)[idx];
    ushort4 o;
    o.x = f2bf_rne(v.x); o.y = f2bf_rne(v.y); o.z = f2bf_rne(v.z); o.w = f2bf_rne(v.w);
    ((ushort4*)Xbf)[idx] = o;
}

// ---------------------- W1[i][v][h] * adj[v,i] -> bf16 W1t[i][h][v] (B^T layout)
__global__ __launch_bounds__(256) void w1_transform_kernel(const float* __restrict__ W1,
                                                           const float* __restrict__ logits,
                                                           unsigned short* __restrict__ W1t) {
    __shared__ float tile[64][65];   // +1 pad breaks transpose-read conflicts
    __shared__ float maskv[64];
    int bx = blockIdx.x;             // grid = 512 * 8
    int i  = bx >> 3;
    int v0 = (bx & 7) << 6;
    int t  = threadIdx.x;
    if (t < 64) {
        int v = v0 + t;
        maskv[t] = (logits[(size_t)v * VV + i] > 0.0f && v != i) ? 1.0f : 0.0f;
    }
    const float* src = W1 + ((size_t)i * VV + v0) * HH;   // 64 v-rows x 64 h, contiguous
    #pragma unroll
    for (int j = 0; j < 16; ++j) {
        int idx = j * 256 + t;
        int vr = idx >> 6, h = idx & 63;
        tile[vr][h] = src[idx];
    }
    __syncthreads();
    unsigned short* dst = W1t + (size_t)i * (HH * VV) + v0;
    #pragma unroll
    for (int j = 0; j < 16; ++j) {
        int idx = j * 256 + t;
        int h = idx >> 6, vr = idx & 63;
        dst[(size_t)h * VV + vr] = f2bf_rne(tile[vr][h] * maskv[vr]);
    }
}

// ---------------------------------------------------------------- main GEMM
// Block = (net i, 256 batch rows). 4 waves, each wave: 64 rows x 64 cols,
// acc 4x4 tiles of mfma_f32_16x16x32_bf16. K-loop over V=512 in steps of 32.
__global__ __launch_bounds__(256) void dag_gemm_kernel(
        const unsigned short* __restrict__ Xbf,   // [B][V] bf16
        const unsigned short* __restrict__ W1t,   // [V][H][V] bf16 (masked, B^T)
        const float* __restrict__ b1,             // [V][H]
        const float* __restrict__ W2,             // [V][H]
        const float* __restrict__ b2,             // [V]
        float* __restrict__ out)                  // [B][V]
{
    __shared__ __align__(16) unsigned short Xs[256 * 32];  // 16 KB: 256 rows x 32 k
    __shared__ __align__(16) unsigned short Ws[64 * 32];   //  4 KB:  64 h   x 32 k

    const int t    = threadIdx.x;
    const int wave = t >> 6;
    const int lane = t & 63;
    const int ln   = lane & 15;
    const int quad = lane >> 4;

    const int bx   = blockIdx.x;          // 8192 blocks
    const int i    = bx & (VV - 1);       // consecutive blocks share the X row-chunk (L2)
    const int row0 = (bx >> 9) << 8;      // 256-row chunk

    floatx4 acc[4][4];
    #pragma unroll
    for (int a = 0; a < 4; ++a)
        #pragma unroll
        for (int b = 0; b < 4; ++b)
            acc[a][b] = (floatx4){0.f, 0.f, 0.f, 0.f};

    const unsigned short* wbase = W1t + (size_t)i * (HH * VV);

    for (int k0 = 0; k0 < VV; k0 += 32) {
        // ---- stage X tile: 256 rows x 32 k = 16 KB = 1024 x 16B chunks
        #pragma unroll
        for (int j = 0; j < 4; ++j) {
            int c = j * 256 + t;                 // lane-contiguous within each wave
            int row = c >> 2, sub = c & 3;       // 4 x 16B per row
            gload_lds16(Xbf + (size_t)(row0 + row) * VV + (k0 + sub * 8),
                        (char*)Xs + c * 16);
        }
        // ---- stage W1t tile: 64 h x 32 k = 4 KB = 256 x 16B chunks
        {
            int c = t;
            int h = c >> 2, sub = c & 3;
            gload_lds16(wbase + (size_t)h * VV + (k0 + sub * 8),
                        (char*)Ws + c * 16);
        }
        __syncthreads();   // compiler drains vmcnt(0) before s_barrier

        bf16x8 af[4], bq[4];
        #pragma unroll
        for (int mt = 0; mt < 4; ++mt)
            af[mt] = *(const bf16x8*)&Xs[(wave * 64 + mt * 16 + ln) * 32 + quad * 8];
        #pragma unroll
        for (int nt = 0; nt < 4; ++nt)
            bq[nt] = *(const bf16x8*)&Ws[(nt * 16 + ln) * 32 + quad * 8];
        #pragma unroll
        for (int mt = 0; mt < 4; ++mt)
            #pragma unroll
            for (int nt = 0; nt < 4; ++nt)
                acc[mt][nt] = __builtin_amdgcn_mfma_f32_16x16x32_bf16(
                    af[mt], bq[nt], acc[mt][nt], 0, 0, 0);
        __syncthreads();
    }

    // ---- fused epilogue: relu(acc + b1) . W2 + b2, fp32 throughout
    float b1v[4], w2v[4];
    #pragma unroll
    for (int nt = 0; nt < 4; ++nt) {
        b1v[nt] = b1[i * HH + nt * 16 + ln];
        w2v[nt] = W2[i * HH + nt * 16 + ln];
    }
    const float b2i = b2[i];
    #pragma unroll
    for (int mt = 0; mt < 4; ++mt) {
        #pragma unroll
        for (int r = 0; r < 4; ++r) {
            float p = 0.f;
            #pragma unroll
            for (int nt = 0; nt < 4; ++nt) {
                float hv = acc[mt][nt][r] + b1v[nt];   // C/D: row=quad*4+r, col=nt*16+ln
                hv = hv > 0.f ? hv : 0.f;
                p += hv * w2v[nt];
            }
            // sum the 16 columns held by the 16 lanes of this quad
            p += __shfl_xor(p, 8);
            p += __shfl_xor(p, 4);
            p += __shfl_xor(p, 2);
            p += __shfl_xor(p, 1);
            if (ln == 0) {
                int row = row0 + wave * 64 + mt * 16 + quad * 4 + r;
                out[(size_t)row * VV + i] = p + b2i;
            }
        }
    }
}

// ----------------------------- fallback (no workspace): fp32 vector path
__global__ __launch_bounds__(256) void fallback_kernel(
        const float* __restrict__ X, const float* __restrict__ logits,
        const float* __restrict__ W1, const float* __restrict__ b1,
        const float* __restrict__ W2, const float* __restrict__ b2,
        float* __restrict__ out) {
    __shared__ float Wc[128][64];                 // 32 KB masked W1 k-chunk
    int i   = blockIdx.x & (VV - 1);
    int row = (blockIdx.x >> 9) * 256 + threadIdx.x;
    float acc[64];
    #pragma unroll
    for (int h = 0; h < 64; ++h) acc[h] = 0.f;
    for (int v0 = 0; v0 < VV; v0 += 128) {
        __syncthreads();
        for (int j = 0; j < 32; ++j) {
            int idx = j * 256 + threadIdx.x;
            int vr = idx >> 6, h = idx & 63;
            int v = v0 + vr;
            float m = (logits[(size_t)v * VV + i] > 0.f && v != i) ? 1.f : 0.f;
            Wc[vr][h] = W1[((size_t)i * VV + v) * HH + h] * m;
        }
        __syncthreads();
        for (int vr = 0; vr < 128; ++vr) {
            float xv = X[(size_t)row * VV + v0 + vr];
            #pragma unroll
            for (int h = 0; h < 64; ++h) acc[h] += xv * Wc[vr][h];
        }
    }
    float p = b2[i];
    #pragma unroll
    for (int h = 0; h < 64; ++h) {
        float hv = acc[h] + b1[i * HH + h];
        p += (hv > 0.f ? hv : 0.f) * W2[i * HH + h];
    }
    out[(size_t)row * VV + i] = p;
}

extern "C" void kernel_launch(void* const* d_in, const int* in_sizes, int n_in,
                              void* d_out, int out_size, void* d_ws, size_t ws_size,
                              hipStream_t stream) {
    const float* X      = (const float*)d_in[0];
    const float* logits = (const float*)d_in[1];
    const float* W1     = (const float*)d_in[2];
    const float* b1     = (const float*)d_in[3];
    const float* W2     = (const float*)d_in[4];
    const float* b2     = (const float*)d_in[5];

    float* out     = (float*)d_out;                       // reconstructed [B][V]
    float* adj_out = out + (size_t)BB * VV;               // adj [V][V]

    const size_t xbf_bytes = (size_t)BB * VV * 2;         // 4 MB
    const size_t w1t_bytes = (size_t)VV * HH * VV * 2;    // 32 MB
    const size_t need = xbf_bytes + w1t_bytes;

    hipLaunchKernelGGL(adj_kernel, dim3((VV * VV) / 256), dim3(256), 0, stream,
                       logits, adj_out);

    if (ws_size >= need) {
        unsigned short* Xbf = (unsigned short*)d_ws;
        unsigned short* W1t = (unsigned short*)((char*)d_ws + xbf_bytes);
        hipLaunchKernelGGL(x_convert_kernel, dim3((BB * VV / 4) / 256), dim3(256), 0, stream,
                           X, Xbf);
        hipLaunchKernelGGL(w1_transform_kernel, dim3(VV * (VV / 64)), dim3(256), 0, stream,
                           W1, logits, W1t);
        hipLaunchKernelGGL(dag_gemm_kernel, dim3(VV * (BB / 256)), dim3(256), 0, stream,
                           Xbf, W1t, b1, W2, b2, out);
    } else {
        hipLaunchKernelGGL(fallback_kernel, dim3(VV * (BB / 256)), dim3(256), 0, stream,
                           X, logits, W1, b1, W2, b2, out);
    }
}